// Round 6
// baseline (301.638 us; speedup 1.0000x reference)
//
#include <hip/hip_runtime.h>
#include <hip/hip_bf16.h>
#include <cstdint>
#include <cstddef>

#define B_  16
#define S_  512
#define E_  768
#define NH_ 12
#define D_  64
#define M_  (B_*S_)   // 8192

typedef unsigned short u16;
typedef __attribute__((ext_vector_type(4))) float f32x4;
typedef __attribute__((ext_vector_type(8))) short bf16x8;

#define LOG2E 1.4426950408889634f

__device__ __forceinline__ u16 f2bf(float f){
  union { float fv; uint32_t u; } v; v.fv = f;
  uint32_t u = v.u;
  uint32_t r = u + 0x7fffu + ((u >> 16) & 1u);   // RNE
  return (u16)(r >> 16);
}

// pack 8 fp32 -> 8 bf16 RNE (k-ascending, low u16 first)
__device__ __forceinline__ uint4 pack8(const float4& a, const float4& b){
  float2 p01; p01.x = a.x; p01.y = a.y;
  float2 p23; p23.x = a.z; p23.y = a.w;
  float2 p45; p45.x = b.x; p45.y = b.y;
  float2 p67; p67.x = b.z; p67.y = b.w;
  __hip_bfloat162 h0 = __float22bfloat162_rn(p01);
  __hip_bfloat162 h1 = __float22bfloat162_rn(p23);
  __hip_bfloat162 h2 = __float22bfloat162_rn(p45);
  __hip_bfloat162 h3 = __float22bfloat162_rn(p67);
  uint4 r;
  r.x = *reinterpret_cast<const unsigned int*>(&h0);
  r.y = *reinterpret_cast<const unsigned int*>(&h1);
  r.z = *reinterpret_cast<const unsigned int*>(&h2);
  r.w = *reinterpret_cast<const unsigned int*>(&h3);
  return r;
}

// ---------------- prep: W transpose only ----------------
__global__ __launch_bounds__(256) void prep_kernel(
    const float* __restrict__ Wq, const float* __restrict__ Wk,
    const float* __restrict__ Wv, u16* __restrict__ WtBase)
{
  __shared__ float t[32][33];
  const int tt = blockIdx.x;               // 0..1727 = 24*24*3
  int z = tt / 576, rem = tt % 576;
  int byi = rem / 24, bxi = rem % 24;
  const float* W = (z == 0) ? Wq : ((z == 1) ? Wk : Wv);
  u16* Wt = WtBase + (size_t)z * E_ * E_;
  int bx0 = bxi * 32, by0 = byi * 32;
  int tx = threadIdx.x & 31, ty = threadIdx.x >> 5;
  #pragma unroll
  for (int i = 0; i < 32; i += 8)
    t[ty + i][tx] = W[(size_t)(by0 + ty + i) * E_ + bx0 + tx];
  __syncthreads();
  #pragma unroll
  for (int i = 0; i < 32; i += 8)
    Wt[(size_t)(bx0 + ty + i) * E_ + by0 + tx] = f2bf(t[tx][ty + i]);
}

// ---------------- R12: fused QKV+attention, barrier-free phase G ----------------
// R11 post-mortem: fusion cut bytes (71MB) but broke concurrency -- 350 GB/s
// effective, Mfma 8%, 36 lockstep barriers each draining a 1-deep stage with
// A-loads issued at use. Phase G has ZERO cross-wave LDS hazards (K/V/Q
// epilogue writes are wave-own chunks), so ALL phase-G barriers are removed:
//  - B operand: per-wave direct bf16x8 global loads (all waves read the same
//    W addresses -> L1 broadcast after first miss). Verified equivalent to
//    R11's staged/swizzled mapping: lane l gets Wt[h*64+ni*16+col0][kt*64+
//    ks*32+quad*8+0..7].
//  - A operand: fp32 loads double-buffered in registers (static names a0/a1),
//    next-kt loads in flight during current kt's 32 MFMAs.
// One __syncthreads total (before phase A). Epilogue layouts + phase A are
// byte-identical to R11 (which PASSED).
__global__ __launch_bounds__(512, 2) void fused_kernel(
    const float* __restrict__ X, const u16* __restrict__ WtBase,
    const float* __restrict__ bq, const float* __restrict__ bk, const float* __restrict__ bv,
    const float* __restrict__ mask, float* __restrict__ out)
{
  extern __shared__ u16 lds[];
  u16* lK  = lds;                  // 32768 u16: chunk = key_tile*8 + ks*4 + nt
  u16* lV  = lds + 32768;          // 32768 u16: V^T chunks; early: per-wave Q scratch
  u16* lPb = lds + 65536;          // 8192 u16: attn lP (8 waves x 1024)
  float* biasS = (float*)(lds + 73728);  // 512 floats

  // XCD-locality swizzle: xcd = blk&7 handles b in {2*xcd, 2*xcd+1}, all 12 h
  const int blk = blockIdx.x;
  const int xcd = blk & 7, idx = blk >> 3;          // idx 0..23
  const int b = xcd * 2 + (idx >= 12 ? 1 : 0);
  const int h = (idx >= 12) ? (idx - 12) : idx;

  const int tid = threadIdx.x, lane = tid & 63, wave = tid >> 6;
  const int col0 = lane & 15, quad = lane >> 4;
  const float C1 = 0.125f * LOG2E;

  if (tid < S_) biasS[tid] = mask[b * S_ + tid] * (-1.0e9f * LOG2E);

  // per-lane operand bases
  const float* XA = X + ((size_t)(b * S_ + wave * 64 + col0)) * E_ + quad * 8;
  const u16*   WB = WtBase + (size_t)(h * 64 + col0) * E_ + quad * 8;

  f32x4 acc[4][4];
  #pragma unroll
  for (int i = 0; i < 4; ++i)
    #pragma unroll
    for (int j = 0; j < 4; ++j) acc[i][j] = (f32x4){0.f,0.f,0.f,0.f};

  bf16x8 qf[4][2];   // persists into attention
  bf16x8 a0[4][2], a1[4][2];

  auto loadA = [&](int kt, bf16x8 (&af)[4][2]){
    #pragma unroll
    for (int mi = 0; mi < 4; ++mi)
      #pragma unroll
      for (int ks = 0; ks < 2; ++ks){
        const float* p = XA + (size_t)mi * 16 * E_ + kt * 64 + ks * 32;
        float4 x0 = *reinterpret_cast<const float4*>(p);
        float4 x1 = *reinterpret_cast<const float4*>(p + 4);
        uint4 u = pack8(x0, x1);
        af[mi][ks] = *reinterpret_cast<const bf16x8*>(&u);
      }
  };
  auto mm = [&](bf16x8 (&af)[4][2], const u16* Wz, int kt){
    #pragma unroll
    for (int ks = 0; ks < 2; ++ks){
      bf16x8 bfr[4];
      #pragma unroll
      for (int ni = 0; ni < 4; ++ni)
        bfr[ni] = *reinterpret_cast<const bf16x8*>(Wz + (size_t)ni * 16 * E_ + kt * 64 + ks * 32);
      #pragma unroll
      for (int mi = 0; mi < 4; ++mi)
        #pragma unroll
        for (int ni = 0; ni < 4; ++ni)
          acc[mi][ni] = __builtin_amdgcn_mfma_f32_16x16x32_bf16(af[mi][ks], bfr[ni], acc[mi][ni], 0, 0, 0);
    }
  };

  // ---- phase G: Q,K,V GEMMs (no barriers) ----
  #pragma unroll 1
  for (int z = 0; z < 3; ++z){
    const u16* Wz = WB + (size_t)z * E_ * E_;
    loadA(0, a0);
    #pragma unroll 1
    for (int kt = 0; kt < 12; kt += 2){
      loadA(kt + 1, a1);              // in flight during mm(a0)
      mm(a0, Wz, kt);
      if (kt < 10) loadA(kt + 2, a0); // in flight during mm(a1)
      mm(a1, Wz, kt + 1);
    }

    // epilogue for z (identical layouts to R11, which passed)
    const float* bz = (z == 0) ? bq : ((z == 1) ? bk : bv);
    float bvv[4];
    #pragma unroll
    for (int ni = 0; ni < 4; ++ni) bvv[ni] = bz[h*64 + ni*16 + col0];
    if (z < 2){
      u16* dst = (z == 0) ? lV : lK;   // Q scratch uses lV region (own-wave chunks)
      #pragma unroll
      for (int mi = 0; mi < 4; ++mi)
        #pragma unroll
        for (int ni = 0; ni < 4; ++ni){
          int chunk = (z == 0) ? (wave*8 + mi*2 + (ni>>1))
                               : (wave*8 + (ni>>1)*4 + mi);
          int base = chunk*512 + (((ni&1)*2 + (col0>>3))*16 + quad*4)*8 + (col0 & 7);
          #pragma unroll
          for (int r = 0; r < 4; ++r)
            dst[base + r*8] = f2bf(acc[mi][ni][r] + bvv[ni]);
        }
      if (z == 0){
        #pragma unroll
        for (int g = 0; g < 4; ++g)
          #pragma unroll
          for (int ks = 0; ks < 2; ++ks)
            qf[g][ks] = *reinterpret_cast<const bf16x8*>(&lV[(wave*8 + g*2 + ks)*512 + lane*8]);
      }
    } else {
      // V^T[d][s]: lane's r=0..3 are 4 consecutive s -> b64 writes
      #pragma unroll
      for (int mi = 0; mi < 4; ++mi)
        #pragma unroll
        for (int ni = 0; ni < 4; ++ni){
          int chunk = wave*8 + ((mi & 2) >> 1)*4 + ni;
          int off = chunk*512 + (((mi&1)*2 + (quad>>1))*16 + col0)*8 + (quad & 1)*4;
          float2 ab; ab.x = acc[mi][ni][0] + bvv[ni]; ab.y = acc[mi][ni][1] + bvv[ni];
          float2 cd; cd.x = acc[mi][ni][2] + bvv[ni]; cd.y = acc[mi][ni][3] + bvv[ni];
          __hip_bfloat162 h01 = __float22bfloat162_rn(ab);
          __hip_bfloat162 h23 = __float22bfloat162_rn(cd);
          uint2 pw;
          pw.x = *reinterpret_cast<unsigned int*>(&h01);
          pw.y = *reinterpret_cast<unsigned int*>(&h23);
          *reinterpret_cast<uint2*>(&lV[off]) = pw;
        }
    }
    #pragma unroll
    for (int i = 0; i < 4; ++i)
      #pragma unroll
      for (int j = 0; j < 4; ++j) acc[i][j] = (f32x4){0.f,0.f,0.f,0.f};
  }
  __syncthreads();   // the ONLY block barrier: lK/lV/bias complete & visible

  // ---- phase A: attention from LDS (no barriers; identical to R11) ----
  f32x4 o[4][4];
  #pragma unroll
  for (int g = 0; g < 4; ++g)
    #pragma unroll
    for (int i = 0; i < 4; ++i) o[g][i] = (f32x4){0.f,0.f,0.f,0.f};
  float psum[4] = {0.f, 0.f, 0.f, 0.f};
  u16* lP = lPb + wave * 1024;            // per-wave, reused across g (DS in-order)

  #pragma unroll 1
  for (int st = 0; st < 8; ++st){
    bf16x8 kf[2][4], vf[2][4];
    #pragma unroll
    for (int ks = 0; ks < 2; ++ks)
      #pragma unroll
      for (int nt = 0; nt < 4; ++nt)
        kf[ks][nt] = *reinterpret_cast<const bf16x8*>(&lK[(st*8 + ks*4 + nt)*512 + lane*8]);
    #pragma unroll
    for (int ks2 = 0; ks2 < 2; ++ks2)
      #pragma unroll
      for (int nd = 0; nd < 4; ++nd)
        vf[ks2][nd] = *reinterpret_cast<const bf16x8*>(&lV[(st*8 + ks2*4 + nd)*512 + lane*8]);
    float4 bb[4];
    #pragma unroll
    for (int nt = 0; nt < 4; ++nt)
      bb[nt] = *reinterpret_cast<const float4*>(&biasS[st*64 + nt*16 + quad*4]);

    #pragma unroll
    for (int g = 0; g < 4; ++g){
      f32x4 sc[4];
      #pragma unroll
      for (int nt = 0; nt < 4; ++nt) sc[nt] = (f32x4){0.f,0.f,0.f,0.f};
      #pragma unroll
      for (int ks = 0; ks < 2; ++ks)
        #pragma unroll
        for (int nt = 0; nt < 4; ++nt)
          sc[nt] = __builtin_amdgcn_mfma_f32_16x16x32_bf16(kf[ks][nt], qf[g][ks], sc[nt], 0, 0, 0);
      #pragma unroll
      for (int nt = 0; nt < 4; ++nt){
        float p0 = exp2f(sc[nt][0] * C1 + bb[nt].x);
        float p1 = exp2f(sc[nt][1] * C1 + bb[nt].y);
        float p2 = exp2f(sc[nt][2] * C1 + bb[nt].z);
        float p3 = exp2f(sc[nt][3] * C1 + bb[nt].w);
        psum[g] += (p0 + p1) + (p2 + p3);
        float2 ab; ab.x = p0; ab.y = p1;
        float2 cd; cd.x = p2; cd.y = p3;
        __hip_bfloat162 h01 = __float22bfloat162_rn(ab);
        __hip_bfloat162 h23 = __float22bfloat162_rn(cd);
        uint2 pw;
        pw.x = *reinterpret_cast<unsigned int*>(&h01);
        pw.y = *reinterpret_cast<unsigned int*>(&h23);
        int addr = (nt >> 1)*512 + (((nt & 1)*2 + (quad >> 1))*16 + col0)*8 + (quad & 1)*4;
        *reinterpret_cast<uint2*>(&lP[addr]) = pw;
      }
      #pragma unroll
      for (int ks2 = 0; ks2 < 2; ++ks2){
        bf16x8 pf = *reinterpret_cast<const bf16x8*>(&lP[ks2*512 + lane*8]);
        #pragma unroll
        for (int nd = 0; nd < 4; ++nd)
          o[g][nd] = __builtin_amdgcn_mfma_f32_16x16x32_bf16(pf, vf[ks2][nd], o[g][nd], 0, 0, 0);
      }
    }
  }

  // epilogue
  #pragma unroll
  for (int g = 0; g < 4; ++g){
    float tot = psum[g];
    tot += __shfl_xor(tot, 16, 64);
    tot += __shfl_xor(tot, 32, 64);
    #pragma unroll
    for (int r = 0; r < 4; ++r){
      int s = wave*64 + g*16 + quad*4 + r;
      float lr = __shfl(tot, (lane & 48) | (quad*4 + r), 64);
      float inv = 1.0f / lr;
      #pragma unroll
      for (int nd = 0; nd < 4; ++nd){
        int d = nd*16 + col0;
        out[((size_t)b * S_ + s) * E_ + h*D_ + d] = o[g][nd][r] * inv;
      }
    }
  }
}

extern "C" void kernel_launch(void* const* d_in, const int* in_sizes, int n_in,
                              void* d_out, int out_size, void* d_ws, size_t ws_size,
                              hipStream_t stream){
  const float* X    = (const float*)d_in[0];
  const float* mask = (const float*)d_in[1];
  const float* Wq   = (const float*)d_in[2];
  const float* bq   = (const float*)d_in[3];
  const float* Wk   = (const float*)d_in[4];
  const float* bk   = (const float*)d_in[5];
  const float* Wv   = (const float*)d_in[6];
  const float* bv   = (const float*)d_in[7];
  float* out = (float*)d_out;

  u16* Wt = (u16*)d_ws;   // 3 x 768 x 768 bf16 = 3.5 MB

  prep_kernel<<<1728, 256, 0, stream>>>(Wq, Wk, Wv, Wt);
  fused_kernel<<<192, 512, 149504, stream>>>(X, Wt, bq, bk, bv, mask, out);
}

// Round 7
// 243.419 us; speedup vs baseline: 1.2392x; 1.2392x over previous
//
#include <hip/hip_runtime.h>
#include <hip/hip_bf16.h>
#include <cstdint>
#include <cstddef>

#define B_  16
#define S_  512
#define E_  768
#define NH_ 12
#define D_  64
#define M_  (B_*S_)   // 8192

typedef unsigned short u16;
typedef __attribute__((ext_vector_type(4))) float f32x4;
typedef __attribute__((ext_vector_type(8))) short bf16x8;

#define LOG2E 1.4426950408889634f

__device__ __forceinline__ u16 f2bf(float f){
  union { float fv; uint32_t u; } v; v.fv = f;
  uint32_t u = v.u;
  uint32_t r = u + 0x7fffu + ((u >> 16) & 1u);   // RNE
  return (u16)(r >> 16);
}

// async global->LDS, 16B per lane, dest = (wave-uniform) base + lane*16
__device__ __forceinline__ void gload_lds16(const u16* g, u16* l){
  __builtin_amdgcn_global_load_lds(
      (const __attribute__((address_space(1))) void*)g,
      (__attribute__((address_space(3))) void*)l, 16, 0, 0);
}

// ---------------- prep: cast X (blocks 0..6143) + transpose W (blocks 6144..7871) ----------------
__global__ __launch_bounds__(256) void prep_kernel(
    const float* __restrict__ X, u16* __restrict__ Xb,
    const float* __restrict__ Wq, const float* __restrict__ Wk,
    const float* __restrict__ Wv, u16* __restrict__ WtBase)
{
  __shared__ float t[32][33];
  const int bx = blockIdx.x;
  if (bx < 6144){
    int i = bx * 256 + threadIdx.x;          // n4 = 8192*768/4 = 1572864 exactly
    float4 v = reinterpret_cast<const float4*>(X)[i];
    ushort4 o;
    o.x = f2bf(v.x); o.y = f2bf(v.y); o.z = f2bf(v.z); o.w = f2bf(v.w);
    reinterpret_cast<ushort4*>(Xb)[i] = o;
  } else {
    int tt = bx - 6144;                      // 0..1727 = 24*24*3
    int z = tt / 576, rem = tt % 576;
    int byi = rem / 24, bxi = rem % 24;
    const float* W = (z == 0) ? Wq : ((z == 1) ? Wk : Wv);
    u16* Wt = WtBase + (size_t)z * E_ * E_;
    int bx0 = bxi * 32, by0 = byi * 32;
    int tx = threadIdx.x & 31, ty = threadIdx.x >> 5;
    #pragma unroll
    for (int i = 0; i < 32; i += 8)
      t[ty + i][tx] = W[(size_t)(by0 + ty + i) * E_ + bx0 + tx];
    __syncthreads();
    #pragma unroll
    for (int i = 0; i < 32; i += 8)
      Wt[(size_t)(bx0 + ty + i) * E_ + by0 + tx] = f2bf(t[tx][ty + i]);
  }
}

// ---------------- fused QKV GEMM ----------------
// R13: PARALLELISM round. Post-mortem of R0/R8/R9/R10: all schedule variants
// had exactly 4608 waves (grid x block fixed) and all tie at ~82us with every
// pipe idle -- the wall is wave-level concurrency, not schedule or bytes.
// (Little's law: ~1.25 effective blocks/CU x 12 lockstep barrier-iters x ~1us
// exposed latency = 81us.) Fix: 64x64 tiles, 256 thr, grid (128,12,3) =
// 4608 blocks = 18432 waves (4x), LDS 32KB -> 5 blocks/CU so other blocks'
// MFMAs cover each block's barrier drain (m114 TLP mechanism). Chunk layout,
// XOR swizzle, pre-swizzled gload source, 2-buffer schedule all identical to
// the PASSED R8 kernel, just at half tile scale (wave tile 32x32, acc[2][2]).
__global__ __launch_bounds__(256, 4) void qkv_gemm_kernel(
    const u16* __restrict__ Xb, const u16* __restrict__ WtBase,
    const float* __restrict__ bq, const float* __restrict__ bk, const float* __restrict__ bv,
    u16* __restrict__ Qb, u16* __restrict__ Kb, u16* __restrict__ VtB)
{
  __shared__ u16 lA[2][8 * 512];   // 2 x 8KB; chunk c = rg*2 + kh (16 rows x 32 k)
  __shared__ u16 lB[2][8 * 512];
  const int z = blockIdx.z;
  const u16* Wt = WtBase + (size_t)z * E_ * E_;
  const float* bias = (z == 0) ? bq : ((z == 1) ? bk : bv);
  const int m0 = blockIdx.x * 64;
  const int n0 = blockIdx.y * 64;
  const int tid = threadIdx.x;
  const int lane = tid & 63;
  const int wave = tid >> 6;               // 0..3
  const int wm = wave & 1, wn = wave >> 1; // 2x2 waves of 32x32
  const int col0 = lane & 15, quad = lane >> 4;
  const int rslot = quad*16 + (col0 ^ (quad << 1));
  // pre-swizzled source coords: lane l fills LDS slot l, so it fetches the
  // (row,oct) that slot l holds: oct=l>>4, row=(l&15)^(oct<<1)  [R8-verified]
  const int oct_l = lane >> 4;
  const int row_l = (lane & 15) ^ (oct_l << 1);

  f32x4 acc[2][2];
  #pragma unroll
  for (int i = 0; i < 2; ++i)
    #pragma unroll
    for (int j = 0; j < 2; ++j)
      acc[i][j] = (f32x4){0.f, 0.f, 0.f, 0.f};

  // per-wave staging sources: row-group rg = wave (rows wave*16..+15)
  const u16* gA = Xb + (size_t)(m0 + wave*16 + row_l) * E_ + oct_l*8;
  const u16* gB = Wt + (size_t)(n0 + wave*16 + row_l) * E_ + oct_l*8;

  auto stage = [&](int k0, int buf){       // 4 gloads/wave
    gload_lds16(gA + k0,      &lA[buf][(wave*2    )*512]);
    gload_lds16(gA + k0 + 32, &lA[buf][(wave*2 + 1)*512]);
    gload_lds16(gB + k0,      &lB[buf][(wave*2    )*512]);
    gload_lds16(gB + k0 + 32, &lB[buf][(wave*2 + 1)*512]);
  };
  stage(0, 0);

  #pragma unroll 1
  for (int st = 0; st < 12; ++st){         // 12 K-steps of 64 (E_=768)
    const int cur = st & 1;
    __syncthreads();   // drains staging of buf[cur]; retires reads of buf[cur^1]
    if (st < 11) stage((st + 1) * 64, cur ^ 1);
    const u16* la = &lA[cur][0];
    const u16* lb = &lB[cur][0];
    #pragma unroll
    for (int ks = 0; ks < 2; ++ks){
      bf16x8 af[2], bfr[2];
      #pragma unroll
      for (int mi = 0; mi < 2; ++mi)
        af[mi] = *reinterpret_cast<const bf16x8*>(&la[((wm*2 + mi)*2 + ks)*512 + rslot*8]);
      #pragma unroll
      for (int ni = 0; ni < 2; ++ni)
        bfr[ni] = *reinterpret_cast<const bf16x8*>(&lb[((wn*2 + ni)*2 + ks)*512 + rslot*8]);
      #pragma unroll
      for (int mi = 0; mi < 2; ++mi)
        #pragma unroll
        for (int ni = 0; ni < 2; ++ni)
          acc[mi][ni] = __builtin_amdgcn_mfma_f32_16x16x32_bf16(af[mi], bfr[ni], acc[mi][ni], 0, 0, 0);
    }
  }

  const int h = blockIdx.y >> 0;           // 64-wide n-tile == one head: h = n>>6
  #pragma unroll
  for (int mi = 0; mi < 2; ++mi){
    #pragma unroll
    for (int ni = 0; ni < 2; ++ni){
      int n = n0 + wn*32 + ni*16 + col0;
      float bval = bias[n];
      int d = n & 63;
      #pragma unroll
      for (int r = 0; r < 4; ++r){
        int m = m0 + wm*32 + mi*16 + quad*4 + r;
        int b = m >> 9, s = m & 511;
        u16 obf = f2bf(acc[mi][ni][r] + bval);
        size_t bh = (size_t)b * NH_ + h;
        if (z == 0)      Qb[(bh * S_ + s) * D_ + d] = obf;
        else if (z == 1) Kb[(bh * S_ + s) * D_ + d] = obf;
        else             VtB[(bh * D_ + d) * S_ + s] = obf;  // transposed for attention
      }
    }
  }
}

// ---------------- flash attention (S^T, FIXED-MAX softmax) — unchanged from R0 ----------------
__global__ __launch_bounds__(256) void attn_kernel(
    const u16* __restrict__ Qb, const u16* __restrict__ Kb, const u16* __restrict__ VtB,
    const float* __restrict__ mask, float* __restrict__ out)
{
  __shared__ u16 lK[2][8 * 512];   // 16 KB
  __shared__ u16 lV[2][8 * 512];   // 16 KB
  __shared__ u16 lP[8 * 1024];     // 16 KB: (wave*2+g)*1024, per-wave (no barrier)
  __shared__ float biasS[S_];
  const int bh = blockIdx.x;
  const int qt = blockIdx.y;
  const int b = bh / NH_, h = bh % NH_;
  const int tid = threadIdx.x, lane = tid & 63, wave = tid >> 6;
  const int col0 = lane & 15, quad = lane >> 4;
  const int ls = lane & 15, lk = lane >> 4;      // staging row / k-octet
  const float C1 = 0.125f * LOG2E;               // score scale folded with log2e

  for (int i = tid; i < S_; i += 256)
    biasS[i] = mask[b * S_ + i] * (-1.0e9f * LOG2E);   // exp2 domain

  const u16* Kbh = Kb  + (size_t)bh * S_ * D_;
  const u16* Vbh = VtB + (size_t)bh * D_ * S_;

  // Q fragments: 2 groups x 16 rows (B-operand; same layout as A)
  bf16x8 qf[2][2];
  #pragma unroll
  for (int g = 0; g < 2; ++g){
    int qrow = qt*128 + wave*32 + g*16 + col0;
    #pragma unroll
    for (int ks = 0; ks < 2; ++ks)
      qf[g][ks] = *reinterpret_cast<const bf16x8*>(
          Qb + ((size_t)bh * S_ + qrow) * D_ + ks*32 + quad*8);
  }

  // staging: waves 0-1 -> 8 K chunks, waves 2-3 -> 8 Vt chunks; identity slot map
  uint4 rg[4];
  auto issue = [&](int st){
    if (wave < 2){
      #pragma unroll
      for (int gg = 0; gg < 4; ++gg){
        int c = wave*4 + gg, ks = c >> 2, nt = c & 3;
        rg[gg] = *reinterpret_cast<const uint4*>(
            Kbh + (size_t)(st*64 + nt*16 + ls) * D_ + ks*32 + lk*8);
      }
    } else {
      #pragma unroll
      for (int gg = 0; gg < 4; ++gg){
        int c = (wave - 2)*4 + gg, ks2 = c >> 2, nd = c & 3;
        rg[gg] = *reinterpret_cast<const uint4*>(
            Vbh + (size_t)(nd*16 + ls) * S_ + st*64 + ks2*32 + lk*8);
      }
    }
  };
  issue(0);

  f32x4 o[2][4];
  #pragma unroll
  for (int g = 0; g < 2; ++g)
    #pragma unroll
    for (int i = 0; i < 4; ++i) o[g][i] = (f32x4){0.f, 0.f, 0.f, 0.f};
  float psum[2] = {0.f, 0.f};   // per-lane partial row-sums (16 keys/lane/group/iter)

  #pragma unroll 1
  for (int st = 0; st < 8; ++st){
    const int cur = st & 1;
    if (wave < 2){
      #pragma unroll
      for (int gg = 0; gg < 4; ++gg)
        *reinterpret_cast<uint4*>(&lK[cur][(wave*4 + gg)*512 + lane*8]) = rg[gg];
    } else {
      #pragma unroll
      for (int gg = 0; gg < 4; ++gg)
        *reinterpret_cast<uint4*>(&lV[cur][((wave - 2)*4 + gg)*512 + lane*8]) = rg[gg];
    }
    __syncthreads();            // single barrier: other buffer's readers done last iter
    if (st < 7) issue(st + 1);  // prefetch during compute

    // scores transposed, both groups: 64 keys (rows) x 16 q (cols)
    f32x4 sc[2][4];
    #pragma unroll
    for (int g = 0; g < 2; ++g)
      #pragma unroll
      for (int nt = 0; nt < 4; ++nt) sc[g][nt] = (f32x4){0.f, 0.f, 0.f, 0.f};
    #pragma unroll
    for (int ks = 0; ks < 2; ++ks){
      bf16x8 kf[4];
      #pragma unroll
      for (int nt = 0; nt < 4; ++nt)
        kf[nt] = *reinterpret_cast<const bf16x8*>(&lK[cur][(ks*4 + nt)*512 + lane*8]);
      #pragma unroll
      for (int g = 0; g < 2; ++g)
        #pragma unroll
        for (int nt = 0; nt < 4; ++nt)
          sc[g][nt] = __builtin_amdgcn_mfma_f32_16x16x32_bf16(kf[nt], qf[g][ks], sc[g][nt], 0, 0, 0);
    }

    float4 bb[4];
    #pragma unroll
    for (int nt = 0; nt < 4; ++nt)
      bb[nt] = *reinterpret_cast<const float4*>(&biasS[st*64 + nt*16 + quad*4]);

    #pragma unroll
    for (int g = 0; g < 2; ++g){
      #pragma unroll
      for (int nt = 0; nt < 4; ++nt){
        float p0 = exp2f(sc[g][nt][0] * C1 + bb[nt].x);
        float p1 = exp2f(sc[g][nt][1] * C1 + bb[nt].y);
        float p2 = exp2f(sc[g][nt][2] * C1 + bb[nt].z);
        float p3 = exp2f(sc[g][nt][3] * C1 + bb[nt].w);
        psum[g] += (p0 + p1) + (p2 + p3);
        float2 ab; ab.x = p0; ab.y = p1;
        float2 cd; cd.x = p2; cd.y = p3;
        __hip_bfloat162 h01 = __float22bfloat162_rn(ab);
        __hip_bfloat162 h23 = __float22bfloat162_rn(cd);
        uint2 pw;
        pw.x = *reinterpret_cast<unsigned int*>(&h01);
        pw.y = *reinterpret_cast<unsigned int*>(&h23);
        // A-layout addr: chunk=nt>>1, slot=((nt&1)*2+(quad>>1))*16+q, u16 pos=(quad&1)*4+r
        int addr = (wave*2 + g)*1024 + (nt >> 1)*512
                 + (((nt & 1)*2 + (quad >> 1))*16 + col0)*8 + (quad & 1)*4;
        *reinterpret_cast<uint2*>(&lP[addr]) = pw;
      }
    }

    // PV: shared V fragments serve both groups
    #pragma unroll
    for (int ks2 = 0; ks2 < 2; ++ks2){
      bf16x8 pf0 = *reinterpret_cast<const bf16x8*>(&lP[(wave*2 + 0)*1024 + ks2*512 + lane*8]);
      bf16x8 pf1 = *reinterpret_cast<const bf16x8*>(&lP[(wave*2 + 1)*1024 + ks2*512 + lane*8]);
      #pragma unroll
      for (int nd = 0; nd < 4; ++nd){
        bf16x8 vf = *reinterpret_cast<const bf16x8*>(&lV[cur][(ks2*4 + nd)*512 + lane*8]);
        o[0][nd] = __builtin_amdgcn_mfma_f32_16x16x32_bf16(pf0, vf, o[0][nd], 0, 0, 0);
        o[1][nd] = __builtin_amdgcn_mfma_f32_16x16x32_bf16(pf1, vf, o[1][nd], 0, 0, 0);
      }
    }
  }

  // epilogue: finish row-sums (once), normalize, store fp32
  #pragma unroll
  for (int g = 0; g < 2; ++g){
    float tot = psum[g];
    tot += __shfl_xor(tot, 16, 64);
    tot += __shfl_xor(tot, 32, 64);
    #pragma unroll
    for (int r = 0; r < 4; ++r){
      int s = qt*128 + wave*32 + g*16 + quad*4 + r;
      float lr = __shfl(tot, (lane & 48) | (quad*4 + r), 64);
      float inv = 1.0f / lr;
      #pragma unroll
      for (int nd = 0; nd < 4; ++nd){
        int d = nd*16 + col0;
        out[((size_t)b * S_ + s) * E_ + h*D_ + d] = o[g][nd][r] * inv;
      }
    }
  }
}

extern "C" void kernel_launch(void* const* d_in, const int* in_sizes, int n_in,
                              void* d_out, int out_size, void* d_ws, size_t ws_size,
                              hipStream_t stream){
  const float* X    = (const float*)d_in[0];
  const float* mask = (const float*)d_in[1];
  const float* Wq   = (const float*)d_in[2];
  const float* bq   = (const float*)d_in[3];
  const float* Wk   = (const float*)d_in[4];
  const float* bk   = (const float*)d_in[5];
  const float* Wv   = (const float*)d_in[6];
  const float* bv   = (const float*)d_in[7];
  float* out = (float*)d_out;

  // workspace layout (bf16): Xb | Wt x3 | Qb | Kb | Vt  (~51.4 MB total)
  u16* Xb = (u16*)d_ws;
  u16* Wt = Xb + (size_t)M_ * E_;
  u16* Qb = Wt + (size_t)3 * E_ * E_;
  u16* Kb = Qb + (size_t)M_ * E_;
  u16* Vt = Kb + (size_t)M_ * E_;

  prep_kernel<<<6144 + 1728, 256, 0, stream>>>(X, Xb, Wq, Wk, Wv, Wt);
  qkv_gemm_kernel<<<dim3(128, 12, 3), 256, 0, stream>>>(Xb, Wt, bq, bk, bv, Qb, Kb, Vt);
  attn_kernel<<<dim3(192, 4), 256, 0, stream>>>(Qb, Kb, Vt, mask, out);
}

// Round 8
// 198.881 us; speedup vs baseline: 1.5167x; 1.2239x over previous
//
#include <hip/hip_runtime.h>
#include <hip/hip_bf16.h>
#include <cstdint>
#include <cstddef>

#define B_  16
#define S_  512
#define E_  768
#define NH_ 12
#define D_  64
#define M_  (B_*S_)   // 8192

typedef unsigned short u16;
typedef __attribute__((ext_vector_type(4))) float f32x4;
typedef __attribute__((ext_vector_type(8))) short bf16x8;

#define LOG2E 1.4426950408889634f

__device__ __forceinline__ u16 f2bf(float f){
  union { float fv; uint32_t u; } v; v.fv = f;
  uint32_t u = v.u;
  uint32_t r = u + 0x7fffu + ((u >> 16) & 1u);   // RNE
  return (u16)(r >> 16);
}

// ---------------- prep ----------------
// R14 experiment: X-cast with 6 independent float4 loads in flight per thread
// (96B/thread MLP) instead of 1. Every kernel this session -- including this
// pure streaming cast -- ran at ~0.45-0.9 TB/s; the shared property was
// per-thread memory ILP ~= 1. Single-variable test of the MLP theory.
// 1024 blocks x 256 thr x 6 chunks = 1572864 float4 = whole X exactly.
// W-transpose part (blocks 1024..2751) unchanged.
__global__ __launch_bounds__(256) void prep_kernel(
    const float* __restrict__ X, u16* __restrict__ Xb,
    const float* __restrict__ Wq, const float* __restrict__ Wk,
    const float* __restrict__ Wv, u16* __restrict__ WtBase)
{
  __shared__ float t[32][33];
  const int bx = blockIdx.x;
  if (bx < 1024){
    const float4* X4 = reinterpret_cast<const float4*>(X);
    ushort4* O4 = reinterpret_cast<ushort4*>(Xb);
    const int base = bx * 256 + threadIdx.x;    // + j*262144, j=0..5
    float4 v[6];
    #pragma unroll
    for (int j = 0; j < 6; ++j)
      v[j] = X4[base + j * 262144];             // 6 loads issued back-to-back
    #pragma unroll
    for (int j = 0; j < 6; ++j){
      ushort4 o;
      o.x = f2bf(v[j].x); o.y = f2bf(v[j].y); o.z = f2bf(v[j].z); o.w = f2bf(v[j].w);
      O4[base + j * 262144] = o;
    }
  } else {
    int tt = bx - 1024;                         // 0..1727 = 24*24*3
    int z = tt / 576, rem = tt % 576;
    int byi = rem / 24, bxi = rem % 24;
    const float* W = (z == 0) ? Wq : ((z == 1) ? Wk : Wv);
    u16* Wt = WtBase + (size_t)z * E_ * E_;
    int bx0 = bxi * 32, by0 = byi * 32;
    int tx = threadIdx.x & 31, ty = threadIdx.x >> 5;
    #pragma unroll
    for (int i = 0; i < 32; i += 8)
      t[ty + i][tx] = W[(size_t)(by0 + ty + i) * E_ + bx0 + tx];
    __syncthreads();
    #pragma unroll
    for (int i = 0; i < 32; i += 8)
      Wt[(size_t)(bx0 + ty + i) * E_ + by0 + tx] = f2bf(t[tx][ty + i]);
  }
}

// ---------------- fused QKV GEMM (exact R0 best-known: 81us) ----------------
__global__ __launch_bounds__(256) void qkv_gemm_kernel(
    const u16* __restrict__ Xb, const u16* __restrict__ WtBase,
    const float* __restrict__ bq, const float* __restrict__ bk, const float* __restrict__ bv,
    u16* __restrict__ Qb, u16* __restrict__ Kb, u16* __restrict__ VtB)
{
  __shared__ u16 lA[16 * 512];   // 16 chunks x 1KB; chunk c = rg*2 + kh (16 rows x 32 k)
  __shared__ u16 lB[16 * 512];
  const int z = blockIdx.z;
  const u16* Wt = WtBase + (size_t)z * E_ * E_;
  const float* bias = (z == 0) ? bq : ((z == 1) ? bk : bv);
  const int m0 = blockIdx.x * 128;
  const int n0 = blockIdx.y * 128;
  const int tid = threadIdx.x;
  const int lane = tid & 63;
  const int wave = tid >> 6;
  const int wm = wave & 1, wn = wave >> 1;       // 2x2 waves of 64x64
  const int col0 = lane & 15, quad = lane >> 4;
  const int srow = lane >> 2, soct = lane & 3;
  const int sslot = soct*16 + (srow ^ (soct << 1));
  const int rslot = quad*16 + (col0 ^ (quad << 1));

  f32x4 acc[4][4];
  #pragma unroll
  for (int i = 0; i < 4; ++i)
    #pragma unroll
    for (int j = 0; j < 4; ++j)
      acc[i][j] = (f32x4){0.f, 0.f, 0.f, 0.f};

  #pragma unroll 1
  for (int k0 = 0; k0 < E_; k0 += 64){
    __syncthreads();
    uint4 va[4], vb[4];
    #pragma unroll
    for (int i = 0; i < 4; ++i){
      int rh = i >> 1, kh = i & 1;
      int grow = rh*64 + wave*16 + srow;
      va[i] = *reinterpret_cast<const uint4*>(Xb + (size_t)(m0 + grow) * E_ + k0 + kh*32 + soct*8);
      vb[i] = *reinterpret_cast<const uint4*>(Wt + (size_t)(n0 + grow) * E_ + k0 + kh*32 + soct*8);
    }
    #pragma unroll
    for (int i = 0; i < 4; ++i){
      int rh = i >> 1, kh = i & 1;
      int c = (rh*4 + wave)*2 + kh;
      *reinterpret_cast<uint4*>(&lA[c*512 + sslot*8]) = va[i];
      *reinterpret_cast<uint4*>(&lB[c*512 + sslot*8]) = vb[i];
    }
    __syncthreads();
    #pragma unroll
    for (int ks = 0; ks < 2; ++ks){
      bf16x8 af[4], bfr[4];
      #pragma unroll
      for (int mi = 0; mi < 4; ++mi)
        af[mi] = *reinterpret_cast<const bf16x8*>(&lA[((wm*4 + mi)*2 + ks)*512 + rslot*8]);
      #pragma unroll
      for (int ni = 0; ni < 4; ++ni)
        bfr[ni] = *reinterpret_cast<const bf16x8*>(&lB[((wn*4 + ni)*2 + ks)*512 + rslot*8]);
      #pragma unroll
      for (int mi = 0; mi < 4; ++mi)
        #pragma unroll
        for (int ni = 0; ni < 4; ++ni)
          acc[mi][ni] = __builtin_amdgcn_mfma_f32_16x16x32_bf16(af[mi], bfr[ni], acc[mi][ni], 0, 0, 0);
    }
  }

  #pragma unroll
  for (int mi = 0; mi < 4; ++mi){
    #pragma unroll
    for (int ni = 0; ni < 4; ++ni){
      int n = n0 + wn*64 + ni*16 + col0;
      float bval = bias[n];
      int h = n >> 6, d = n & 63;
      #pragma unroll
      for (int r = 0; r < 4; ++r){
        int m = m0 + wm*64 + mi*16 + quad*4 + r;
        int b = m >> 9, s = m & 511;
        u16 obf = f2bf(acc[mi][ni][r] + bval);
        size_t bh = (size_t)b * NH_ + h;
        if (z == 0)      Qb[(bh * S_ + s) * D_ + d] = obf;
        else if (z == 1) Kb[(bh * S_ + s) * D_ + d] = obf;
        else             VtB[(bh * D_ + d) * S_ + s] = obf;  // transposed for attention
      }
    }
  }
}

// ---------------- flash attention (exact R0 best-known) ----------------
__global__ __launch_bounds__(256) void attn_kernel(
    const u16* __restrict__ Qb, const u16* __restrict__ Kb, const u16* __restrict__ VtB,
    const float* __restrict__ mask, float* __restrict__ out)
{
  __shared__ u16 lK[2][8 * 512];   // 16 KB
  __shared__ u16 lV[2][8 * 512];   // 16 KB
  __shared__ u16 lP[8 * 1024];     // 16 KB: (wave*2+g)*1024, per-wave (no barrier)
  __shared__ float biasS[S_];
  const int bh = blockIdx.x;
  const int qt = blockIdx.y;
  const int b = bh / NH_, h = bh % NH_;
  const int tid = threadIdx.x, lane = tid & 63, wave = tid >> 6;
  const int col0 = lane & 15, quad = lane >> 4;
  const int ls = lane & 15, lk = lane >> 4;      // staging row / k-octet
  const float C1 = 0.125f * LOG2E;               // score scale folded with log2e

  for (int i = tid; i < S_; i += 256)
    biasS[i] = mask[b * S_ + i] * (-1.0e9f * LOG2E);   // exp2 domain

  const u16* Kbh = Kb  + (size_t)bh * S_ * D_;
  const u16* Vbh = VtB + (size_t)bh * D_ * S_;

  // Q fragments: 2 groups x 16 rows (B-operand; same layout as A)
  bf16x8 qf[2][2];
  #pragma unroll
  for (int g = 0; g < 2; ++g){
    int qrow = qt*128 + wave*32 + g*16 + col0;
    #pragma unroll
    for (int ks = 0; ks < 2; ++ks)
      qf[g][ks] = *reinterpret_cast<const bf16x8*>(
          Qb + ((size_t)bh * S_ + qrow) * D_ + ks*32 + quad*8);
  }

  // staging: waves 0-1 -> 8 K chunks, waves 2-3 -> 8 Vt chunks; identity slot map
  uint4 rg[4];
  auto issue = [&](int st){
    if (wave < 2){
      #pragma unroll
      for (int gg = 0; gg < 4; ++gg){
        int c = wave*4 + gg, ks = c >> 2, nt = c & 3;
        rg[gg] = *reinterpret_cast<const uint4*>(
            Kbh + (size_t)(st*64 + nt*16 + ls) * D_ + ks*32 + lk*8);
      }
    } else {
      #pragma unroll
      for (int gg = 0; gg < 4; ++gg){
        int c = (wave - 2)*4 + gg, ks2 = c >> 2, nd = c & 3;
        rg[gg] = *reinterpret_cast<const uint4*>(
            Vbh + (size_t)(nd*16 + ls) * S_ + st*64 + ks2*32 + lk*8);
      }
    }
  };
  issue(0);

  f32x4 o[2][4];
  #pragma unroll
  for (int g = 0; g < 2; ++g)
    #pragma unroll
    for (int i = 0; i < 4; ++i) o[g][i] = (f32x4){0.f, 0.f, 0.f, 0.f};
  float psum[2] = {0.f, 0.f};   // per-lane partial row-sums (16 keys/lane/group/iter)

  #pragma unroll 1
  for (int st = 0; st < 8; ++st){
    const int cur = st & 1;
    if (wave < 2){
      #pragma unroll
      for (int gg = 0; gg < 4; ++gg)
        *reinterpret_cast<uint4*>(&lK[cur][(wave*4 + gg)*512 + lane*8]) = rg[gg];
    } else {
      #pragma unroll
      for (int gg = 0; gg < 4; ++gg)
        *reinterpret_cast<uint4*>(&lV[cur][((wave - 2)*4 + gg)*512 + lane*8]) = rg[gg];
    }
    __syncthreads();            // single barrier: other buffer's readers done last iter
    if (st < 7) issue(st + 1);  // prefetch during compute

    // scores transposed, both groups: 64 keys (rows) x 16 q (cols)
    f32x4 sc[2][4];
    #pragma unroll
    for (int g = 0; g < 2; ++g)
      #pragma unroll
      for (int nt = 0; nt < 4; ++nt) sc[g][nt] = (f32x4){0.f, 0.f, 0.f, 0.f};
    #pragma unroll
    for (int ks = 0; ks < 2; ++ks){
      bf16x8 kf[4];
      #pragma unroll
      for (int nt = 0; nt < 4; ++nt)
        kf[nt] = *reinterpret_cast<const bf16x8*>(&lK[cur][(ks*4 + nt)*512 + lane*8]);
      #pragma unroll
      for (int g = 0; g < 2; ++g)
        #pragma unroll
        for (int nt = 0; nt < 4; ++nt)
          sc[g][nt] = __builtin_amdgcn_mfma_f32_16x16x32_bf16(kf[nt], qf[g][ks], sc[g][nt], 0, 0, 0);
    }

    float4 bb[4];
    #pragma unroll
    for (int nt = 0; nt < 4; ++nt)
      bb[nt] = *reinterpret_cast<const float4*>(&biasS[st*64 + nt*16 + quad*4]);

    #pragma unroll
    for (int g = 0; g < 2; ++g){
      #pragma unroll
      for (int nt = 0; nt < 4; ++nt){
        float p0 = exp2f(sc[g][nt][0] * C1 + bb[nt].x);
        float p1 = exp2f(sc[g][nt][1] * C1 + bb[nt].y);
        float p2 = exp2f(sc[g][nt][2] * C1 + bb[nt].z);
        float p3 = exp2f(sc[g][nt][3] * C1 + bb[nt].w);
        psum[g] += (p0 + p1) + (p2 + p3);
        float2 ab; ab.x = p0; ab.y = p1;
        float2 cd; cd.x = p2; cd.y = p3;
        __hip_bfloat162 h01 = __float22bfloat162_rn(ab);
        __hip_bfloat162 h23 = __float22bfloat162_rn(cd);
        uint2 pw;
        pw.x = *reinterpret_cast<unsigned int*>(&h01);
        pw.y = *reinterpret_cast<unsigned int*>(&h23);
        // A-layout addr: chunk=nt>>1, slot=((nt&1)*2+(quad>>1))*16+q, u16 pos=(quad&1)*4+r
        int addr = (wave*2 + g)*1024 + (nt >> 1)*512
                 + (((nt & 1)*2 + (quad >> 1))*16 + col0)*8 + (quad & 1)*4;
        *reinterpret_cast<uint2*>(&lP[addr]) = pw;
      }
    }

    // PV: shared V fragments serve both groups
    #pragma unroll
    for (int ks2 = 0; ks2 < 2; ++ks2){
      bf16x8 pf0 = *reinterpret_cast<const bf16x8*>(&lP[(wave*2 + 0)*1024 + ks2*512 + lane*8]);
      bf16x8 pf1 = *reinterpret_cast<const bf16x8*>(&lP[(wave*2 + 1)*1024 + ks2*512 + lane*8]);
      #pragma unroll
      for (int nd = 0; nd < 4; ++nd){
        bf16x8 vf = *reinterpret_cast<const bf16x8*>(&lV[cur][(ks2*4 + nd)*512 + lane*8]);
        o[0][nd] = __builtin_amdgcn_mfma_f32_16x16x32_bf16(pf0, vf, o[0][nd], 0, 0, 0);
        o[1][nd] = __builtin_amdgcn_mfma_f32_16x16x32_bf16(pf1, vf, o[1][nd], 0, 0, 0);
      }
    }
  }

  // epilogue: finish row-sums (once), normalize, store fp32
  #pragma unroll
  for (int g = 0; g < 2; ++g){
    float tot = psum[g];
    tot += __shfl_xor(tot, 16, 64);
    tot += __shfl_xor(tot, 32, 64);
    #pragma unroll
    for (int r = 0; r < 4; ++r){
      int s = qt*128 + wave*32 + g*16 + quad*4 + r;
      float lr = __shfl(tot, (lane & 48) | (quad*4 + r), 64);
      float inv = 1.0f / lr;
      #pragma unroll
      for (int nd = 0; nd < 4; ++nd){
        int d = nd*16 + col0;
        out[((size_t)b * S_ + s) * E_ + h*D_ + d] = o[g][nd][r] * inv;
      }
    }
  }
}

extern "C" void kernel_launch(void* const* d_in, const int* in_sizes, int n_in,
                              void* d_out, int out_size, void* d_ws, size_t ws_size,
                              hipStream_t stream){
  const float* X    = (const float*)d_in[0];
  const float* mask = (const float*)d_in[1];
  const float* Wq   = (const float*)d_in[2];
  const float* bq   = (const float*)d_in[3];
  const float* Wk   = (const float*)d_in[4];
  const float* bk   = (const float*)d_in[5];
  const float* Wv   = (const float*)d_in[6];
  const float* bv   = (const float*)d_in[7];
  float* out = (float*)d_out;

  // workspace layout (bf16): Xb | Wt x3 | Qb | Kb | Vt  (~51.4 MB total)
  u16* Xb = (u16*)d_ws;
  u16* Wt = Xb + (size_t)M_ * E_;
  u16* Qb = Wt + (size_t)3 * E_ * E_;
  u16* Kb = Qb + (size_t)M_ * E_;
  u16* Vt = Kb + (size_t)M_ * E_;

  prep_kernel<<<1024 + 1728, 256, 0, stream>>>(X, Xb, Wq, Wk, Wv, Wt);
  qkv_gemm_kernel<<<dim3(64, 6, 3), 256, 0, stream>>>(Xb, Wt, bq, bk, bv, Qb, Kb, Vt);
  attn_kernel<<<dim3(192, 4), 256, 0, stream>>>(Qb, Kb, Vt, mask, out);
}